// Round 7
// baseline (392.925 us; speedup 1.0000x reference)
//
#include <hip/hip_runtime.h>
#include <hip/hip_bf16.h>
#include <math.h>

#define S_LEN 2048
#define NH    32
#define NKV   8
#define HD    64
#define HID2  4096   // 2*HID (K of projections)
#define HIDQ  2048   // H*D
#define HIDK  512    // HK*D

typedef __attribute__((ext_vector_type(8))) __bf16 bf16x8;
typedef __attribute__((ext_vector_type(4))) __bf16 bf16x4;
typedef __attribute__((ext_vector_type(4))) float  f32x4;

__device__ __forceinline__ f32x4 mfma16(bf16x8 a, bf16x8 b, f32x4 c) {
  return __builtin_amdgcn_mfma_f32_16x16x32_bf16(a, b, c, 0, 0, 0);
}

__device__ __forceinline__ void gload_lds16(const void* g, void* l) {
  __builtin_amdgcn_global_load_lds(
      (const __attribute__((address_space(1))) void*)g,
      (__attribute__((address_space(3))) void*)l, 16, 0, 0);
}

__device__ __forceinline__ unsigned int packbf(float a, float b) {
  __bf16 ba = (__bf16)a, bb = (__bf16)b;
  unsigned short ua = __builtin_bit_cast(unsigned short, ba);
  unsigned short ub = __builtin_bit_cast(unsigned short, bb);
  return (unsigned int)ua | ((unsigned int)ub << 16);
}

// ---------------- merged cast f32 -> bf16 (all 5 tensors, contiguous dst) ----
#define F4_HS 2097152
#define F4_WQ 2097152
#define F4_WK 524288
#define F4_WV 524288
#define F4_WO 1048576
#define F4_TOT (F4_HS + F4_WQ + F4_WK + F4_WV + F4_WO)  // 6291456

__global__ __launch_bounds__(256) void cast_all_k(
    const float* __restrict__ hs, const float* __restrict__ wq,
    const float* __restrict__ wk, const float* __restrict__ wv,
    const float* __restrict__ wo, bf16x4* __restrict__ dst) {
  int i = blockIdx.x * 256 + threadIdx.x;
  if (i >= F4_TOT) return;
  const float* src;
  int off = i;
  if (off < F4_HS) { src = hs; }
  else { off -= F4_HS;
    if (off < F4_WQ) { src = wq; }
    else { off -= F4_WQ;
      if (off < F4_WK) { src = wk; }
      else { off -= F4_WK;
        if (off < F4_WV) { src = wv; }
        else { off -= F4_WV; src = wo; } } } }
  float4 v = reinterpret_cast<const float4*>(src)[off];
  bf16x4 o;
  o[0] = (__bf16)v.x; o[1] = (__bf16)v.y; o[2] = (__bf16)v.z; o[3] = (__bf16)v.w;
  dst[i] = o;
}

// ---------------- RoPE cos/sin table: cs[s*32+j] = (cos, sin) ----------------
__global__ __launch_bounds__(256) void rope_table_k(const int* __restrict__ pos,
                                                    float2* __restrict__ cs) {
  int idx = blockIdx.x * 256 + threadIdx.x;
  if (idx >= S_LEN * 32) return;
  int s = idx >> 5, j = idx & 31;
  float p = (float)pos[s];
  float inv = exp2f(-(float)j * (13.287712379549449f / 32.0f));  // 10000^(-j/32)
  float ang = p * inv;
  float sv, cv;
  sincosf(ang, &sv, &cv);
  cs[idx] = make_float2(cv, sv);
}

// ---------------- merged QKV projection GEMM ----------------
// A[2048,4096] bf16, B[3072,4096] bf16 (rows: 0-2047 WQ, 2048-2559 WK, 2560-3071 WV)
// epilogue per 128-col tile: Q-RoPE -> Qo, K-RoPE -> Ko, V-transpose -> Vto
__global__ __launch_bounds__(256) void gemm_qkv(
    const __bf16* __restrict__ A, const __bf16* __restrict__ B,
    __bf16* __restrict__ Qo, __bf16* __restrict__ Ko, __bf16* __restrict__ Vto,
    const float2* __restrict__ cs) {
  const int K = HID2;
  __shared__ __align__(16) __bf16 Abuf[128 * 32];
  __shared__ __align__(16) __bf16 Bbuf[128 * 32];
  const int tid = threadIdx.x;
  const int w = tid >> 6, l = tid & 63;
  const int wr = w >> 1, wc = w & 1;
  const int row0 = blockIdx.y * 128, col0 = blockIdx.x * 128;
  const int lr = l & 15, lk = (l >> 4) * 8;

  f32x4 acc[4][4] = {};

  const __bf16* Ag = A + (size_t)(row0 + (tid >> 2)) * K + (tid & 3) * 8;
  const __bf16* Bg = B + (size_t)(col0 + (tid >> 2)) * K + (tid & 3) * 8;
  __bf16* AbufW = Abuf + w * 512;
  __bf16* BbufW = Bbuf + w * 512;

  for (int kt = 0; kt < K; kt += 32) {
    gload_lds16(Ag + kt, AbufW);
    gload_lds16(Ag + kt + (size_t)64 * K, AbufW + 2048);
    gload_lds16(Bg + kt, BbufW);
    gload_lds16(Bg + kt + (size_t)64 * K, BbufW + 2048);
    __syncthreads();
    bf16x8 af[4], bfr[4];
#pragma unroll
    for (int i = 0; i < 4; ++i)
      af[i] = *reinterpret_cast<const bf16x8*>(&Abuf[(64 * wr + 16 * i + lr) * 32 + lk]);
#pragma unroll
    for (int j = 0; j < 4; ++j)
      bfr[j] = *reinterpret_cast<const bf16x8*>(&Bbuf[(64 * wc + 16 * j + lr) * 32 + lk]);
#pragma unroll
    for (int i = 0; i < 4; ++i)
#pragma unroll
      for (int j = 0; j < 4; ++j)
        acc[i][j] = mfma16(af[i], bfr[j], acc[i][j]);
    __syncthreads();
  }

  const int mb = row0 + 64 * wr, nb = col0 + 64 * wc;
  const int rsub = (l >> 4) * 4;

  if (col0 < 2560) {  // Q or K: RoPE epilogue
    __bf16* out;
    int ostride, ncol;
    if (col0 < 2048) { out = Qo; ostride = HIDQ; ncol = nb; }
    else             { out = Ko; ostride = HIDK; ncol = nb - 2048; }
#pragma unroll
    for (int i = 0; i < 4; ++i)
#pragma unroll
      for (int r = 0; r < 4; ++r) {
        int m = mb + 16 * i + rsub + r;
#pragma unroll
        for (int j = 0; j < 2; ++j) {
          int d = 16 * j + lr;  // within-head dim (ncol is 64-aligned)
          float2 c = cs[m * 32 + d];
          float x1 = acc[i][j][r];
          float x2 = acc[i][j + 2][r];
          out[(size_t)m * ostride + ncol + d]      = (__bf16)(x1 * c.x - x2 * c.y);
          out[(size_t)m * ostride + ncol + d + 32] = (__bf16)(x2 * c.x + x1 * c.y);
        }
      }
  } else {  // V: transpose store Vto[feature][seq]
    int vb = nb - 2560;
#pragma unroll
    for (int i = 0; i < 4; ++i)
#pragma unroll
      for (int j = 0; j < 4; ++j)
#pragma unroll
        for (int r = 0; r < 4; ++r)
          Vto[(size_t)(vb + 16 * j + lr) * S_LEN + mb + 16 * i + rsub + r] =
              (__bf16)acc[i][j][r];
  }
}

// ---------------- output GEMM: C[M,N] = A[M,K] @ B[N,K]^T, f32 out ----------
__global__ __launch_bounds__(256) void gemm_out(const __bf16* __restrict__ A,
                                                const __bf16* __restrict__ B,
                                                float* __restrict__ out,
                                                int M, int N, int K) {
  __shared__ __align__(16) __bf16 Abuf[128 * 32];
  __shared__ __align__(16) __bf16 Bbuf[128 * 32];
  const int tid = threadIdx.x;
  const int w = tid >> 6, l = tid & 63;
  const int wr = w >> 1, wc = w & 1;
  const int row0 = blockIdx.y * 128, col0 = blockIdx.x * 128;
  const int lr = l & 15, lk = (l >> 4) * 8;

  f32x4 acc[4][4] = {};

  const __bf16* Ag = A + (size_t)(row0 + (tid >> 2)) * K + (tid & 3) * 8;
  const __bf16* Bg = B + (size_t)(col0 + (tid >> 2)) * K + (tid & 3) * 8;
  __bf16* AbufW = Abuf + w * 512;
  __bf16* BbufW = Bbuf + w * 512;

  for (int kt = 0; kt < K; kt += 32) {
    gload_lds16(Ag + kt, AbufW);
    gload_lds16(Ag + kt + (size_t)64 * K, AbufW + 2048);
    gload_lds16(Bg + kt, BbufW);
    gload_lds16(Bg + kt + (size_t)64 * K, BbufW + 2048);
    __syncthreads();
    bf16x8 af[4], bfr[4];
#pragma unroll
    for (int i = 0; i < 4; ++i)
      af[i] = *reinterpret_cast<const bf16x8*>(&Abuf[(64 * wr + 16 * i + lr) * 32 + lk]);
#pragma unroll
    for (int j = 0; j < 4; ++j)
      bfr[j] = *reinterpret_cast<const bf16x8*>(&Bbuf[(64 * wc + 16 * j + lr) * 32 + lk]);
#pragma unroll
    for (int i = 0; i < 4; ++i)
#pragma unroll
      for (int j = 0; j < 4; ++j)
        acc[i][j] = mfma16(af[i], bfr[j], acc[i][j]);
    __syncthreads();
  }

  const int mb = row0 + 64 * wr, nb = col0 + 64 * wc;
  const int rsub = (l >> 4) * 4;
#pragma unroll
  for (int i = 0; i < 4; ++i)
#pragma unroll
    for (int j = 0; j < 4; ++j)
#pragma unroll
      for (int r = 0; r < 4; ++r)
        out[(size_t)(mb + 16 * i + rsub + r) * N + nb + 16 * j + lr] = acc[i][j][r];
}

// ---------------- flash attention v3: KV-split for occupancy ----------------
// Grid (16 pairs, 32 heads, 2 halves). Tiles: A = p (q rows p*64..), B = 31-p.
// half 0: tile A complete (write AO) + tile B it in [0, 16-p)   -> partial 0
// half 1: tile B it in [16-p, 32-p) (includes diagonal)         -> partial 1
// Partials (unnormalized o, m, l) merged by combine_k for tiles 16..31.
struct AttnState {
  f32x4 o[4];
  float mrun, lrun;
};

// Process kv-tiles [it0, it1) of q-tile t for head h. Updates st.
__device__ __forceinline__ void attn_run(const __bf16* __restrict__ Q,
                                         const __bf16* __restrict__ Kc,
                                         const __bf16* __restrict__ Vt,
                                         int h, int kh, int t, int it0, int it1,
                                         int w, int lr, int lg, AttnState& st) {
  const int qbase = t * 64 + w * 16;
  const __bf16* qp = Q + (size_t)(qbase + lr) * HIDQ + h * HD + lg * 8;
  bf16x8 qf0 = *reinterpret_cast<const bf16x8*>(qp);
  bf16x8 qf1 = *reinterpret_cast<const bf16x8*>(qp + 32);

  for (int it = it0; it < it1; ++it) {
    const int kv0 = it * 64;
    const bool diag = (it == t);
    const int nmax = diag ? (w + 1) : 4;  // wave-uniform

    // QK^T swapped: A = K rows (kv), B = Q rows (q). sc[n][r]:
    //   q = qbase + lr, kv = kv0 + 16n + 4*lg + r
    f32x4 sc[4] = {};
    const __bf16* kp = Kc + (size_t)(kv0 + lr) * HIDK + kh * HD + lg * 8;
#pragma unroll
    for (int n = 0; n < 4; ++n) {
      if (n < nmax) {
        bf16x8 k0 = *reinterpret_cast<const bf16x8*>(kp + (size_t)n * 16 * HIDK);
        bf16x8 k1 = *reinterpret_cast<const bf16x8*>(kp + (size_t)n * 16 * HIDK + 32);
        sc[n] = mfma16(k0, qf0, sc[n]);
        sc[n] = mfma16(k1, qf1, sc[n]);
      }
    }

    // V loads hoisted: latency hides under softmax VALU phase
    bf16x8 vf0[4], vf1[4];
    const __bf16* vp = Vt + (size_t)(kh * HD + lr) * S_LEN + kv0 + lg * 8;
#pragma unroll
    for (int dn = 0; dn < 4; ++dn) {
      vf0[dn] = *reinterpret_cast<const bf16x8*>(vp + (size_t)dn * 16 * S_LEN);
      vf1[dn] = *reinterpret_cast<const bf16x8*>(vp + (size_t)dn * 16 * S_LEN + 32);
    }

    // scale + causal mask + in-register row stats
    float pmax = -3e38f;
#pragma unroll
    for (int n = 0; n < 4; ++n)
#pragma unroll
      for (int r = 0; r < 4; ++r) {
        float v = sc[n][r] * 0.125f;
        if (diag && (kv0 + 16 * n + 4 * lg + r > qbase + lr)) v = -3e38f;
        sc[n][r] = v;
        pmax = fmaxf(pmax, v);
      }
    pmax = fmaxf(pmax, __shfl_xor(pmax, 16));
    pmax = fmaxf(pmax, __shfl_xor(pmax, 32));
    float mnew = fmaxf(st.mrun, pmax);
    float alpha = __expf(st.mrun - mnew);
    float psum = 0.f;
#pragma unroll
    for (int n = 0; n < 4; ++n)
#pragma unroll
      for (int r = 0; r < 4; ++r) {
        float pv = __expf(sc[n][r] - mnew);
        sc[n][r] = pv;
        psum += pv;
      }
    psum += __shfl_xor(psum, 16);
    psum += __shfl_xor(psum, 32);
    st.lrun = st.lrun * alpha + psum;
    st.mrun = mnew;
#pragma unroll
    for (int dn = 0; dn < 4; ++dn) st.o[dn] *= alpha;

    // pack P to bf16 words: W0[n][rp] = (p[16n+4lg+2rp], p[..+1])
    unsigned int W0[4][2];
#pragma unroll
    for (int n = 0; n < 4; ++n) {
      W0[n][0] = packbf(sc[n][0], sc[n][1]);
      W0[n][1] = packbf(sc[n][2], sc[n][3]);
    }
    // Exchange into PV B-frag layout: dest lane (lg,lr) word tt needs
    // pack(P[8lg+2tt],P[8lg+2tt+1]) from source lane (2(lg&1)+(tt>>1))*16+lr
    // chunk n=lg>>1 (+2 hi). n is a DEST property -> select after shuffle.
    union BP { unsigned int u[4]; bf16x8 v; };
    BP u0, u1;
#pragma unroll
    for (int tt = 0; tt < 4; ++tt) {
      int src = ((lg & 1) * 2 + (tt >> 1)) * 16 + lr;
      unsigned int a0 = __shfl(W0[0][tt & 1], src);
      unsigned int a1 = __shfl(W0[1][tt & 1], src);
      unsigned int a2 = __shfl(W0[2][tt & 1], src);
      unsigned int a3 = __shfl(W0[3][tt & 1], src);
      u0.u[tt] = (lg & 2) ? a1 : a0;
      u1.u[tt] = (lg & 2) ? a3 : a2;
    }
    bf16x8 bp0 = u0.v, bp1 = u1.v;

    // PV: A = V^T rows (d), B = P^T cols (q). o[dn][r]:
    //   q = qbase + lr, d = 16*dn + 4*lg + r
#pragma unroll
    for (int dn = 0; dn < 4; ++dn) {
      st.o[dn] = mfma16(vf0[dn], bp0, st.o[dn]);
      st.o[dn] = mfma16(vf1[dn], bp1, st.o[dn]);
    }
  }
}

__global__ __launch_bounds__(256) void attn_k(const __bf16* __restrict__ Q,
                                              const __bf16* __restrict__ Kc,
                                              const __bf16* __restrict__ Vt,
                                              __bf16* __restrict__ AO,
                                              float* __restrict__ OP,
                                              float* __restrict__ ML) {
  const int w = threadIdx.x >> 6, l = threadIdx.x & 63;
  const int lr = l & 15, lg = l >> 4;
  const int p = blockIdx.x, h = blockIdx.y, half = blockIdx.z, kh = h >> 2;
  const int tB = 31 - p;

  if (half == 0) {
    // ---- tile A complete ----
    AttnState st;
#pragma unroll
    for (int dn = 0; dn < 4; ++dn) st.o[dn] = f32x4{};
    st.mrun = -3e38f; st.lrun = 0.f;
    attn_run(Q, Kc, Vt, h, kh, p, 0, p + 1, w, lr, lg, st);
    float inv = 1.0f / st.lrun;
    const int qbase = p * 64 + w * 16;
    unsigned int* aout =
        (unsigned int*)(AO + (size_t)(qbase + lr) * HIDQ + h * HD);
#pragma unroll
    for (int dn = 0; dn < 4; ++dn) {
      aout[8 * dn + 2 * lg]     = packbf(st.o[dn][0] * inv, st.o[dn][1] * inv);
      aout[8 * dn + 2 * lg + 1] = packbf(st.o[dn][2] * inv, st.o[dn][3] * inv);
    }
    // ---- tile B prefix: it in [0, 16-p) ----
    AttnState sb;
#pragma unroll
    for (int dn = 0; dn < 4; ++dn) sb.o[dn] = f32x4{};
    sb.mrun = -3e38f; sb.lrun = 0.f;
    attn_run(Q, Kc, Vt, h, kh, tB, 0, 16 - p, w, lr, lg, sb);
    int e = (tB - 16) * 32 + h;  // = (15-p)*32+h
    float* op = OP + (size_t)e * 4096;
    int row = w * 16 + lr;
#pragma unroll
    for (int dn = 0; dn < 4; ++dn)
#pragma unroll
      for (int r = 0; r < 4; ++r)
        op[row * 64 + 16 * dn + 4 * lg + r] = sb.o[dn][r];
    if (lg == 0) {
      ML[e * 128 + row] = sb.mrun;
      ML[e * 128 + 64 + row] = sb.lrun;
    }
  } else {
    // ---- tile B suffix: it in [16-p, 32-p), includes diagonal ----
    AttnState sb;
#pragma unroll
    for (int dn = 0; dn < 4; ++dn) sb.o[dn] = f32x4{};
    sb.mrun = -3e38f; sb.lrun = 0.f;
    attn_run(Q, Kc, Vt, h, kh, tB, 16 - p, 32 - p, w, lr, lg, sb);
    int e = 512 + (tB - 16) * 32 + h;
    float* op = OP + (size_t)e * 4096;
    int row = w * 16 + lr;
#pragma unroll
    for (int dn = 0; dn < 4; ++dn)
#pragma unroll
      for (int r = 0; r < 4; ++r)
        op[row * 64 + 16 * dn + 4 * lg + r] = sb.o[dn][r];
    if (lg == 0) {
      ML[e * 128 + row] = sb.mrun;
      ML[e * 128 + 64 + row] = sb.lrun;
    }
  }
}

// merge the two partials for tiles 16..31 and write AO
__global__ __launch_bounds__(256) void combine_k(const float* __restrict__ OP,
                                                 const float* __restrict__ ML,
                                                 __bf16* __restrict__ AO) {
  int e = blockIdx.x;            // 0..511
  int t = 16 + (e >> 5), h = e & 31;
  int row = threadIdx.x >> 2, d0 = (threadIdx.x & 3) * 16;
  float m0 = ML[e * 128 + row],         l0 = ML[e * 128 + 64 + row];
  float m1 = ML[(512 + e) * 128 + row], l1 = ML[(512 + e) * 128 + 64 + row];
  float m = fmaxf(m0, m1);
  float a0 = __expf(m0 - m), a1 = __expf(m1 - m);
  float inv = 1.0f / (l0 * a0 + l1 * a1);
  const float* o0 = OP + (size_t)e * 4096 + row * 64 + d0;
  const float* o1 = OP + (size_t)(512 + e) * 4096 + row * 64 + d0;
  unsigned int* ao =
      (unsigned int*)(AO + (size_t)(t * 64 + row) * HIDQ + h * HD + d0);
#pragma unroll
  for (int j = 0; j < 8; ++j) {
    float x0 = (o0[2 * j] * a0 + o1[2 * j] * a1) * inv;
    float x1 = (o0[2 * j + 1] * a0 + o1[2 * j + 1] * a1) * inv;
    ao[j] = packbf(x0, x1);
  }
}

extern "C" void kernel_launch(void* const* d_in, const int* in_sizes, int n_in,
                              void* d_out, int out_size, void* d_ws, size_t ws_size,
                              hipStream_t stream) {
  const float* hs  = (const float*)d_in[0];
  const int*   pos = (const int*)d_in[1];
  const float* wq  = (const float*)d_in[2];
  const float* wk  = (const float*)d_in[3];
  const float* wv  = (const float*)d_in[4];
  const float* wo  = (const float*)d_in[5];

  char* ws = (char*)d_ws;
  const size_t MB = (size_t)1 << 20;
  __bf16* Xbf = (__bf16*)(ws + 0 * MB);    // 16 MB [2048 x 4096]
  __bf16* WQb = (__bf16*)(ws + 16 * MB);   // 16 MB [2048 x 4096]  \
  /* WKb = ws+32MB  4 MB [512 x 4096]  | contiguous: B of gemm_qkv (3072 rows) */
  /* WVb = ws+36MB  4 MB [512 x 4096]  / and contiguous cast dst               */
  __bf16* WOb = (__bf16*)(ws + 40 * MB);   //  8 MB [2048 x 2048]
  __bf16* Qb  = (__bf16*)(ws + 48 * MB);   //  8 MB [2048 x 2048]
  __bf16* Kb  = (__bf16*)(ws + 56 * MB);   //  2 MB [2048 x 512]
  __bf16* Vt  = (__bf16*)(ws + 58 * MB);   //  2 MB [512 x 2048]
  __bf16* AOb = (__bf16*)(ws + 60 * MB);   //  8 MB [2048 x 2048]
  float2* CS  = (float2*)(ws + 68 * MB);   // 512 KB [2048 x 32]
  // Attention partials REUSE the Xbf/WQb region (dead after gemm_qkv):
  float* OP = (float*)(ws + 0 * MB);       // 16 MB: [2][512][64][64] f32
  float* ML = (float*)(ws + 16 * MB);      // 512 KB: [2][512][2][64] f32

  cast_all_k<<<F4_TOT / 256, 256, 0, stream>>>(hs, wq, wk, wv, wo, (bf16x4*)ws);
  rope_table_k<<<(S_LEN * 32) / 256, 256, 0, stream>>>(pos, CS);

  gemm_qkv<<<dim3(3072 / 128, S_LEN / 128), 256, 0, stream>>>(
      Xbf, WQb, Qb, Kb, Vt, CS);

  attn_k<<<dim3(16, NH, 2), 256, 0, stream>>>(Qb, Kb, Vt, AOb, OP, ML);
  combine_k<<<512, 256, 0, stream>>>(OP, ML, AOb);

  gemm_out<<<dim3(HIDQ / 128, S_LEN / 128), 256, 0, stream>>>(
      AOb, WOb, (float*)d_out, S_LEN, HIDQ, HIDQ);
}

// Round 9
// 321.452 us; speedup vs baseline: 1.2223x; 1.2223x over previous
//
#include <hip/hip_runtime.h>
#include <hip/hip_bf16.h>
#include <math.h>

#define S_LEN 2048
#define NH    32
#define NKV   8
#define HD    64
#define HID2  4096   // 2*HID (K of projections)
#define HIDQ  2048   // H*D
#define HIDK  512    // HK*D

typedef __attribute__((ext_vector_type(8))) __bf16 bf16x8;
typedef __attribute__((ext_vector_type(4))) __bf16 bf16x4;
typedef __attribute__((ext_vector_type(4))) float  f32x4;

__device__ __forceinline__ f32x4 mfma16(bf16x8 a, bf16x8 b, f32x4 c) {
  return __builtin_amdgcn_mfma_f32_16x16x32_bf16(a, b, c, 0, 0, 0);
}

__device__ __forceinline__ void gload_lds16(const void* g, void* l) {
  __builtin_amdgcn_global_load_lds(
      (const __attribute__((address_space(1))) void*)g,
      (__attribute__((address_space(3))) void*)l, 16, 0, 0);
}

__device__ __forceinline__ unsigned int packbf(float a, float b) {
  __bf16 ba = (__bf16)a, bb = (__bf16)b;
  unsigned short ua = __builtin_bit_cast(unsigned short, ba);
  unsigned short ub = __builtin_bit_cast(unsigned short, bb);
  return (unsigned int)ua | ((unsigned int)ub << 16);
}

// ---------------- merged cast f32 -> bf16 (all 5 tensors, contiguous dst) ----
#define F4_HS 2097152
#define F4_WQ 2097152
#define F4_WK 524288
#define F4_WV 524288
#define F4_WO 1048576
#define F4_TOT (F4_HS + F4_WQ + F4_WK + F4_WV + F4_WO)  // 6291456

__global__ __launch_bounds__(256) void cast_all_k(
    const float* __restrict__ hs, const float* __restrict__ wq,
    const float* __restrict__ wk, const float* __restrict__ wv,
    const float* __restrict__ wo, bf16x4* __restrict__ dst) {
  int i = blockIdx.x * 256 + threadIdx.x;
  if (i >= F4_TOT) return;
  const float* src;
  int off = i;
  if (off < F4_HS) { src = hs; }
  else { off -= F4_HS;
    if (off < F4_WQ) { src = wq; }
    else { off -= F4_WQ;
      if (off < F4_WK) { src = wk; }
      else { off -= F4_WK;
        if (off < F4_WV) { src = wv; }
        else { off -= F4_WV; src = wo; } } } }
  float4 v = reinterpret_cast<const float4*>(src)[off];
  bf16x4 o;
  o[0] = (__bf16)v.x; o[1] = (__bf16)v.y; o[2] = (__bf16)v.z; o[3] = (__bf16)v.w;
  dst[i] = o;
}

// ---------------- RoPE cos/sin table: cs[s*32+j] = (cos, sin) ----------------
__global__ __launch_bounds__(256) void rope_table_k(const int* __restrict__ pos,
                                                    float2* __restrict__ cs) {
  int idx = blockIdx.x * 256 + threadIdx.x;
  if (idx >= S_LEN * 32) return;
  int s = idx >> 5, j = idx & 31;
  float p = (float)pos[s];
  float inv = exp2f(-(float)j * (13.287712379549449f / 32.0f));  // 10000^(-j/32)
  float ang = p * inv;
  float sv, cv;
  sincosf(ang, &sv, &cv);
  cs[idx] = make_float2(cv, sv);
}

// ---------------- merged QKV projection GEMM ----------------
__global__ __launch_bounds__(256) void gemm_qkv(
    const __bf16* __restrict__ A, const __bf16* __restrict__ B,
    __bf16* __restrict__ Qo, __bf16* __restrict__ Ko, __bf16* __restrict__ Vto,
    const float2* __restrict__ cs) {
  const int K = HID2;
  __shared__ __align__(16) __bf16 Abuf[128 * 32];
  __shared__ __align__(16) __bf16 Bbuf[128 * 32];
  const int tid = threadIdx.x;
  const int w = tid >> 6, l = tid & 63;
  const int wr = w >> 1, wc = w & 1;
  const int row0 = blockIdx.y * 128, col0 = blockIdx.x * 128;
  const int lr = l & 15, lk = (l >> 4) * 8;

  f32x4 acc[4][4] = {};

  const __bf16* Ag = A + (size_t)(row0 + (tid >> 2)) * K + (tid & 3) * 8;
  const __bf16* Bg = B + (size_t)(col0 + (tid >> 2)) * K + (tid & 3) * 8;
  __bf16* AbufW = Abuf + w * 512;
  __bf16* BbufW = Bbuf + w * 512;

  for (int kt = 0; kt < K; kt += 32) {
    gload_lds16(Ag + kt, AbufW);
    gload_lds16(Ag + kt + (size_t)64 * K, AbufW + 2048);
    gload_lds16(Bg + kt, BbufW);
    gload_lds16(Bg + kt + (size_t)64 * K, BbufW + 2048);
    __syncthreads();
    bf16x8 af[4], bfr[4];
#pragma unroll
    for (int i = 0; i < 4; ++i)
      af[i] = *reinterpret_cast<const bf16x8*>(&Abuf[(64 * wr + 16 * i + lr) * 32 + lk]);
#pragma unroll
    for (int j = 0; j < 4; ++j)
      bfr[j] = *reinterpret_cast<const bf16x8*>(&Bbuf[(64 * wc + 16 * j + lr) * 32 + lk]);
#pragma unroll
    for (int i = 0; i < 4; ++i)
#pragma unroll
      for (int j = 0; j < 4; ++j)
        acc[i][j] = mfma16(af[i], bfr[j], acc[i][j]);
    __syncthreads();
  }

  const int mb = row0 + 64 * wr, nb = col0 + 64 * wc;
  const int rsub = (l >> 4) * 4;

  if (col0 < 2560) {  // Q or K: RoPE epilogue
    __bf16* out;
    int ostride, ncol;
    if (col0 < 2048) { out = Qo; ostride = HIDQ; ncol = nb; }
    else             { out = Ko; ostride = HIDK; ncol = nb - 2048; }
#pragma unroll
    for (int i = 0; i < 4; ++i)
#pragma unroll
      for (int r = 0; r < 4; ++r) {
        int m = mb + 16 * i + rsub + r;
#pragma unroll
        for (int j = 0; j < 2; ++j) {
          int d = 16 * j + lr;
          float2 c = cs[m * 32 + d];
          float x1 = acc[i][j][r];
          float x2 = acc[i][j + 2][r];
          out[(size_t)m * ostride + ncol + d]      = (__bf16)(x1 * c.x - x2 * c.y);
          out[(size_t)m * ostride + ncol + d + 32] = (__bf16)(x2 * c.x + x1 * c.y);
        }
      }
  } else {  // V: transpose store Vto[feature][seq]
    int vb = nb - 2560;
#pragma unroll
    for (int i = 0; i < 4; ++i)
#pragma unroll
      for (int j = 0; j < 4; ++j)
#pragma unroll
        for (int r = 0; r < 4; ++r)
          Vto[(size_t)(vb + 16 * j + lr) * S_LEN + mb + 16 * i + rsub + r] =
              (__bf16)acc[i][j][r];
  }
}

// ---------------- output GEMM: C[M,N] = A[M,K] @ B[N,K]^T, f32 out ----------
__global__ __launch_bounds__(256) void gemm_out(const __bf16* __restrict__ A,
                                                const __bf16* __restrict__ B,
                                                float* __restrict__ out,
                                                int M, int N, int K) {
  __shared__ __align__(16) __bf16 Abuf[128 * 32];
  __shared__ __align__(16) __bf16 Bbuf[128 * 32];
  const int tid = threadIdx.x;
  const int w = tid >> 6, l = tid & 63;
  const int wr = w >> 1, wc = w & 1;
  const int row0 = blockIdx.y * 128, col0 = blockIdx.x * 128;
  const int lr = l & 15, lk = (l >> 4) * 8;

  f32x4 acc[4][4] = {};

  const __bf16* Ag = A + (size_t)(row0 + (tid >> 2)) * K + (tid & 3) * 8;
  const __bf16* Bg = B + (size_t)(col0 + (tid >> 2)) * K + (tid & 3) * 8;
  __bf16* AbufW = Abuf + w * 512;
  __bf16* BbufW = Bbuf + w * 512;

  for (int kt = 0; kt < K; kt += 32) {
    gload_lds16(Ag + kt, AbufW);
    gload_lds16(Ag + kt + (size_t)64 * K, AbufW + 2048);
    gload_lds16(Bg + kt, BbufW);
    gload_lds16(Bg + kt + (size_t)64 * K, BbufW + 2048);
    __syncthreads();
    bf16x8 af[4], bfr[4];
#pragma unroll
    for (int i = 0; i < 4; ++i)
      af[i] = *reinterpret_cast<const bf16x8*>(&Abuf[(64 * wr + 16 * i + lr) * 32 + lk]);
#pragma unroll
    for (int j = 0; j < 4; ++j)
      bfr[j] = *reinterpret_cast<const bf16x8*>(&Bbuf[(64 * wc + 16 * j + lr) * 32 + lk]);
#pragma unroll
    for (int i = 0; i < 4; ++i)
#pragma unroll
      for (int j = 0; j < 4; ++j)
        acc[i][j] = mfma16(af[i], bfr[j], acc[i][j]);
    __syncthreads();
  }

  const int mb = row0 + 64 * wr, nb = col0 + 64 * wc;
  const int rsub = (l >> 4) * 4;
#pragma unroll
  for (int i = 0; i < 4; ++i)
#pragma unroll
    for (int j = 0; j < 4; ++j)
#pragma unroll
      for (int r = 0; r < 4; ++r)
        out[(size_t)(mb + 16 * i + rsub + r) * N + nb + 16 * j + lr] = acc[i][j][r];
}

// ---------------- flash attention v4: LDS-staged K/V (request dedup) --------
// K/V tiles (8 KB each) staged once per block per iteration via global_load_lds
// (double-buffered), XOR-swizzled: physical chunk cp at row rw holds logical
// chunk cp^(rw&7). Both stage (pre-swizzled global src) and reads apply it.
struct AttnState {
  f32x4 o[4];
  float mrun, lrun;
};

// Stage the 64x64 bf16 K-tile and V-tile for kv0 into kb/vb (4096 bf16 each).
__device__ __forceinline__ void stage_kv(const __bf16* __restrict__ Kc,
                                         const __bf16* __restrict__ Vt,
                                         int kh, int kv0, int w, int l,
                                         __bf16* kb, __bf16* vb) {
  // lane supplies physical chunks c0 = w*64+l and c1 = c0+256 (16 B each)
  const int c0 = w * 64 + l, c1 = c0 + 256;
  const int rw0 = c0 >> 3, cl0 = (c0 & 7) ^ (rw0 & 7);
  const int rw1 = c1 >> 3, cl1 = (c1 & 7) ^ (rw1 & 7);
  // LDS dst: wave-uniform base; HW adds lane*16
  gload_lds16(Kc + (size_t)(kv0 + rw0) * HIDK + kh * HD + cl0 * 8, kb + w * 512);
  gload_lds16(Kc + (size_t)(kv0 + rw1) * HIDK + kh * HD + cl1 * 8, kb + 2048 + w * 512);
  gload_lds16(Vt + (size_t)(kh * HD + rw0) * S_LEN + kv0 + cl0 * 8, vb + w * 512);
  gload_lds16(Vt + (size_t)(kh * HD + rw1) * S_LEN + kv0 + cl1 * 8, vb + 2048 + w * 512);
}

__device__ __forceinline__ void attn_run(const __bf16* __restrict__ Q,
                                         const __bf16* __restrict__ Kc,
                                         const __bf16* __restrict__ Vt,
                                         __bf16* kb0, __bf16* kb1,
                                         __bf16* vb0, __bf16* vb1,
                                         int h, int kh, int t, int it0, int it1,
                                         int w, int lr, int lg, int l,
                                         AttnState& st) {
  const int qbase = t * 64 + w * 16;
  const __bf16* qp = Q + (size_t)(qbase + lr) * HIDQ + h * HD + lg * 8;
  bf16x8 qf0 = *reinterpret_cast<const bf16x8*>(qp);
  bf16x8 qf1 = *reinterpret_cast<const bf16x8*>(qp + 32);
  const int x = lr & 7;  // swizzle key (row&7 is lr&7 for all frag rows)

  __syncthreads();  // prior reader of buf0 done (2nd call in half-0)
  stage_kv(Kc, Vt, kh, it0 * 64, w, l, kb0, vb0);
  int cur = 0;

  for (int it = it0; it < it1; ++it) {
    __syncthreads();  // staged buf `cur` ready (sync drains vmcnt)
    __bf16* kb = cur ? kb1 : kb0;
    __bf16* vb = cur ? vb1 : vb0;
    if (it + 1 < it1)
      stage_kv(Kc, Vt, kh, (it + 1) * 64, w, l,
               cur ? kb0 : kb1, cur ? vb0 : vb1);

    const int kv0 = it * 64;
    const bool diag = (it == t);
    const int nmax = diag ? (w + 1) : 4;  // wave-uniform

    // QK^T swapped: A = K rows (kv), B = Q rows (q). sc[n][r]:
    //   q = qbase + lr, kv = kv0 + 16n + 4*lg + r
    f32x4 sc[4] = {};
#pragma unroll
    for (int n = 0; n < 4; ++n) {
      if (n < nmax) {
        const __bf16* kbase = kb + (lr + 16 * n) * 64;
        bf16x8 k0 = *reinterpret_cast<const bf16x8*>(kbase + ((lg ^ x) * 8));
        bf16x8 k1 = *reinterpret_cast<const bf16x8*>(kbase + (((4 + lg) ^ x) * 8));
        sc[n] = mfma16(k0, qf0, sc[n]);
        sc[n] = mfma16(k1, qf1, sc[n]);
      }
    }

    // V fragment reads hoisted: LDS latency hides under softmax VALU phase
    bf16x8 vf0[4], vf1[4];
#pragma unroll
    for (int dn = 0; dn < 4; ++dn) {
      const __bf16* vbase = vb + (lr + 16 * dn) * 64;
      vf0[dn] = *reinterpret_cast<const bf16x8*>(vbase + ((lg ^ x) * 8));
      vf1[dn] = *reinterpret_cast<const bf16x8*>(vbase + (((4 + lg) ^ x) * 8));
    }

    // scale + causal mask + in-register row stats
    float pmax = -3e38f;
#pragma unroll
    for (int n = 0; n < 4; ++n)
#pragma unroll
      for (int r = 0; r < 4; ++r) {
        float v = sc[n][r] * 0.125f;
        if (diag && (kv0 + 16 * n + 4 * lg + r > qbase + lr)) v = -3e38f;
        sc[n][r] = v;
        pmax = fmaxf(pmax, v);
      }
    pmax = fmaxf(pmax, __shfl_xor(pmax, 16));
    pmax = fmaxf(pmax, __shfl_xor(pmax, 32));
    float mnew = fmaxf(st.mrun, pmax);
    float alpha = __expf(st.mrun - mnew);
    float psum = 0.f;
#pragma unroll
    for (int n = 0; n < 4; ++n)
#pragma unroll
      for (int r = 0; r < 4; ++r) {
        float pv = __expf(sc[n][r] - mnew);
        sc[n][r] = pv;
        psum += pv;
      }
    psum += __shfl_xor(psum, 16);
    psum += __shfl_xor(psum, 32);
    st.lrun = st.lrun * alpha + psum;
    st.mrun = mnew;
#pragma unroll
    for (int dn = 0; dn < 4; ++dn) st.o[dn] *= alpha;

    // pack P to bf16 words: W0[n][rp] = (p[16n+4lg+2rp], p[..+1])
    unsigned int W0[4][2];
#pragma unroll
    for (int n = 0; n < 4; ++n) {
      W0[n][0] = packbf(sc[n][0], sc[n][1]);
      W0[n][1] = packbf(sc[n][2], sc[n][3]);
    }
    // Exchange into PV B-frag layout: dest lane (lg,lr) word tt needs
    // pack(P[8lg+2tt],P[8lg+2tt+1]) from src lane (2(lg&1)+(tt>>1))*16+lr,
    // chunk n=lg>>1 (+2 hi). n is a DEST property -> select after shuffle.
    union BP { unsigned int u[4]; bf16x8 v; };
    BP u0, u1;
#pragma unroll
    for (int tt = 0; tt < 4; ++tt) {
      int src = ((lg & 1) * 2 + (tt >> 1)) * 16 + lr;
      unsigned int a0 = __shfl(W0[0][tt & 1], src);
      unsigned int a1 = __shfl(W0[1][tt & 1], src);
      unsigned int a2 = __shfl(W0[2][tt & 1], src);
      unsigned int a3 = __shfl(W0[3][tt & 1], src);
      u0.u[tt] = (lg & 2) ? a1 : a0;
      u1.u[tt] = (lg & 2) ? a3 : a2;
    }
    bf16x8 bp0 = u0.v, bp1 = u1.v;

    // PV: A = V^T rows (d), B = P^T cols (q). o[dn][r]:
    //   q = qbase + lr, d = 16*dn + 4*lg + r
#pragma unroll
    for (int dn = 0; dn < 4; ++dn) {
      st.o[dn] = mfma16(vf0[dn], bp0, st.o[dn]);
      st.o[dn] = mfma16(vf1[dn], bp1, st.o[dn]);
    }
    cur ^= 1;
  }
}

__global__ __launch_bounds__(256) void attn_k(const __bf16* __restrict__ Q,
                                              const __bf16* __restrict__ Kc,
                                              const __bf16* __restrict__ Vt,
                                              __bf16* __restrict__ AO,
                                              float* __restrict__ OP,
                                              float* __restrict__ ML) {
  __shared__ __align__(16) __bf16 KB0[4096], KB1[4096], VB0[4096], VB1[4096];
  const int w = threadIdx.x >> 6, l = threadIdx.x & 63;
  const int lr = l & 15, lg = l >> 4;
  const int p = blockIdx.x, h = blockIdx.y, half = blockIdx.z, kh = h >> 2;
  const int tB = 31 - p;

  if (half == 0) {
    // ---- tile A complete ----
    AttnState st;
#pragma unroll
    for (int dn = 0; dn < 4; ++dn) st.o[dn] = f32x4{};
    st.mrun = -3e38f; st.lrun = 0.f;
    attn_run(Q, Kc, Vt, KB0, KB1, VB0, VB1, h, kh, p, 0, p + 1, w, lr, lg, l, st);
    float inv = 1.0f / st.lrun;
    const int qbase = p * 64 + w * 16;
    unsigned int* aout =
        (unsigned int*)(AO + (size_t)(qbase + lr) * HIDQ + h * HD);
#pragma unroll
    for (int dn = 0; dn < 4; ++dn) {
      aout[8 * dn + 2 * lg]     = packbf(st.o[dn][0] * inv, st.o[dn][1] * inv);
      aout[8 * dn + 2 * lg + 1] = packbf(st.o[dn][2] * inv, st.o[dn][3] * inv);
    }
    // ---- tile B prefix: it in [0, 16-p) ----
    AttnState sb;
#pragma unroll
    for (int dn = 0; dn < 4; ++dn) sb.o[dn] = f32x4{};
    sb.mrun = -3e38f; sb.lrun = 0.f;
    attn_run(Q, Kc, Vt, KB0, KB1, VB0, VB1, h, kh, tB, 0, 16 - p, w, lr, lg, l, sb);
    int e = (tB - 16) * 32 + h;
    float* op = OP + (size_t)e * 4096;
    int row = w * 16 + lr;
#pragma unroll
    for (int dn = 0; dn < 4; ++dn)
#pragma unroll
      for (int r = 0; r < 4; ++r)
        op[row * 64 + 16 * dn + 4 * lg + r] = sb.o[dn][r];
    if (lg == 0) {
      ML[e * 128 + row] = sb.mrun;
      ML[e * 128 + 64 + row] = sb.lrun;
    }
  } else {
    // ---- tile B suffix: it in [16-p, 32-p), includes diagonal ----
    AttnState sb;
#pragma unroll
    for (int dn = 0; dn < 4; ++dn) sb.o[dn] = f32x4{};
    sb.mrun = -3e38f; sb.lrun = 0.f;
    attn_run(Q, Kc, Vt, KB0, KB1, VB0, VB1, h, kh, tB, 16 - p, 32 - p, w, lr, lg, l, sb);
    int e = 512 + (tB - 16) * 32 + h;
    float* op = OP + (size_t)e * 4096;
    int row = w * 16 + lr;
#pragma unroll
    for (int dn = 0; dn < 4; ++dn)
#pragma unroll
      for (int r = 0; r < 4; ++r)
        op[row * 64 + 16 * dn + 4 * lg + r] = sb.o[dn][r];
    if (lg == 0) {
      ML[e * 128 + row] = sb.mrun;
      ML[e * 128 + 64 + row] = sb.lrun;
    }
  }
}

// merge the two partials for tiles 16..31 and write AO
__global__ __launch_bounds__(256) void combine_k(const float* __restrict__ OP,
                                                 const float* __restrict__ ML,
                                                 __bf16* __restrict__ AO) {
  int e = blockIdx.x;            // 0..511
  int t = 16 + (e >> 5), h = e & 31;
  int row = threadIdx.x >> 2, d0 = (threadIdx.x & 3) * 16;
  float m0 = ML[e * 128 + row],         l0 = ML[e * 128 + 64 + row];
  float m1 = ML[(512 + e) * 128 + row], l1 = ML[(512 + e) * 128 + 64 + row];
  float m = fmaxf(m0, m1);
  float a0 = __expf(m0 - m), a1 = __expf(m1 - m);
  float inv = 1.0f / (l0 * a0 + l1 * a1);
  const float* o0 = OP + (size_t)e * 4096 + row * 64 + d0;
  const float* o1 = OP + (size_t)(512 + e) * 4096 + row * 64 + d0;
  unsigned int* ao =
      (unsigned int*)(AO + (size_t)(t * 64 + row) * HIDQ + h * HD + d0);
#pragma unroll
  for (int j = 0; j < 8; ++j) {
    float x0 = (o0[2 * j] * a0 + o1[2 * j] * a1) * inv;
    float x1 = (o0[2 * j + 1] * a0 + o1[2 * j + 1] * a1) * inv;
    ao[j] = packbf(x0, x1);
  }
}

extern "C" void kernel_launch(void* const* d_in, const int* in_sizes, int n_in,
                              void* d_out, int out_size, void* d_ws, size_t ws_size,
                              hipStream_t stream) {
  const float* hs  = (const float*)d_in[0];
  const int*   pos = (const int*)d_in[1];
  const float* wq  = (const float*)d_in[2];
  const float* wk  = (const float*)d_in[3];
  const float* wv  = (const float*)d_in[4];
  const float* wo  = (const float*)d_in[5];

  char* ws = (char*)d_ws;
  const size_t MB = (size_t)1 << 20;
  __bf16* Xbf = (__bf16*)(ws + 0 * MB);    // 16 MB [2048 x 4096]
  __bf16* WQb = (__bf16*)(ws + 16 * MB);   // 16 MB [2048 x 4096]  \
  /* WKb = ws+32MB  4 MB [512 x 4096]  | contiguous: B of gemm_qkv (3072 rows) */
  /* WVb = ws+36MB  4 MB [512 x 4096]  / and contiguous cast dst               */
  __bf16* WOb = (__bf16*)(ws + 40 * MB);   //  8 MB [2048 x 2048]
  __bf16* Qb  = (__bf16*)(ws + 48 * MB);   //  8 MB [2048 x 2048]
  __bf16* Kb  = (__bf16*)(ws + 56 * MB);   //  2 MB [2048 x 512]
  __bf16* Vt  = (__bf16*)(ws + 58 * MB);   //  2 MB [512 x 2048]
  __bf16* AOb = (__bf16*)(ws + 60 * MB);   //  8 MB [2048 x 2048]
  float2* CS  = (float2*)(ws + 68 * MB);   // 512 KB [2048 x 32]
  // Attention partials REUSE the Xbf/WQb region (dead after gemm_qkv):
  float* OP = (float*)(ws + 0 * MB);       // 16 MB: [2][512][64][64] f32
  float* ML = (float*)(ws + 16 * MB);      // 512 KB: [2][512][2][64] f32

  cast_all_k<<<F4_TOT / 256, 256, 0, stream>>>(hs, wq, wk, wv, wo, (bf16x4*)ws);
  rope_table_k<<<(S_LEN * 32) / 256, 256, 0, stream>>>(pos, CS);

  gemm_qkv<<<dim3(3072 / 128, S_LEN / 128), 256, 0, stream>>>(
      Xbf, WQb, Qb, Kb, Vt, CS);

  attn_k<<<dim3(16, NH, 2), 256, 0, stream>>>(Qb, Kb, Vt, AOb, OP, ML);
  combine_k<<<512, 256, 0, stream>>>(OP, ML, AOb);

  gemm_out<<<dim3(HIDQ / 128, S_LEN / 128), 256, 0, stream>>>(
      AOb, WOb, (float*)d_out, S_LEN, HIDQ, HIDQ);
}